// Round 9
// baseline (84.673 us; speedup 1.0000x reference)
//
#include <hip/hip_runtime.h>
#include <hip/hip_fp16.h>

#define EMBED 128
#define NRBF 6
#define VOCAB 100
#define EBLOCK 1024
#define EGRID 256
#define CHUNK 512                  // edges per pipeline chunk
#define PC (CHUNK / 32)            // 16 edges per 32-lane group per chunk
#define TABLE_F (VOCAB * EMBED * 2 + NRBF * EMBED)   // 26368 floats = 105,472 B
#define SMEM_MAIN (TABLE_F * 4 + 2 * CHUNK * 16)     // 121,856 B
// fallback geometry (R8)
#define GROUPS 32
#define CPG 37
#define HALF_E (GROUPS * CPG)
#define BCHUNK (2 * HALF_E)
#define SMEM_FB (TABLE_F * 4 + HALF_E * 16)

// ---------------------------------------------------------------------------
// Precompute (206 blocks):
//   T1[v][d] = sum_j emb[v][j]*Wd[j][d] + b[d];  T2[v][d] = sum emb*Wd[128+j];
//   Wc[k][d] = sum_j W_edge[k][j]*Wd[256+j][d]
// ---------------------------------------------------------------------------
__global__ __launch_bounds__(EMBED) void precompute_kernel(
    const float* __restrict__ W_edge,
    const float* __restrict__ emb,
    const float* __restrict__ Wd,
    const float* __restrict__ b,
    float* __restrict__ T1,
    float* __restrict__ T2,
    float* __restrict__ Wc)
{
    const int d = threadIdx.x;
    const int v = blockIdx.x;
    if (v < 2 * VOCAB) {
        const int row = (v < VOCAB) ? v : v - VOCAB;
        const int woff = (v < VOCAB) ? 0 : EMBED;
        __shared__ float hrow[EMBED];
        hrow[d] = emb[row * EMBED + d];
        __syncthreads();
        float acc = (v < VOCAB) ? b[d] : 0.0f;
        #pragma unroll 8
        for (int j = 0; j < EMBED; ++j)
            acc += hrow[j] * Wd[(woff + j) * EMBED + d];
        if (v < VOCAB) T1[row * EMBED + d] = acc;
        else           T2[row * EMBED + d] = acc;
    } else {
        const int k = v - 2 * VOCAB;
        float acc = 0.0f;
        #pragma unroll 8
        for (int j = 0; j < EMBED; ++j)
            acc += W_edge[k * EMBED + j] * Wd[(2 * EMBED + j) * EMBED + d];
        Wc[k * EMBED + d] = acc;
    }
}

// ---------------------------------------------------------------------------
// Pack pass: meta[e] = {rbf as 6x fp16, z[a] | z[b]<<16}. One thread/edge,
// fully parallel -> the 2-hop chain latency is hidden by sheer TLP.
// Edges in [E, Epad) get zero meta (safe LDS index 0 in the consumer).
// ---------------------------------------------------------------------------
__global__ __launch_bounds__(256) void pack_kernel(
    const float* __restrict__ e_rbf,
    const int*   __restrict__ z,
    const int*   __restrict__ nbr,
    uint4* __restrict__ meta, int E, int Epad)
{
    const int e = blockIdx.x * 256 + threadIdx.x;
    if (e >= Epad) return;
    uint4 m = make_uint4(0u, 0u, 0u, 0u);
    if (e < E) {
        const int2 nn = *reinterpret_cast<const int2*>(nbr + 2 * e);
        const float* rp = e_rbf + (long)e * NRBF;
        const float2 a = *reinterpret_cast<const float2*>(rp + 0);
        const float2 bb = *reinterpret_cast<const float2*>(rp + 2);
        const float2 c = *reinterpret_cast<const float2*>(rp + 4);
        __half2 ha = __float22half2_rn(a);
        __half2 hb = __float22half2_rn(bb);
        __half2 hc = __float22half2_rn(c);
        m.x = *reinterpret_cast<unsigned*>(&ha);
        m.y = *reinterpret_cast<unsigned*>(&hb);
        m.z = *reinterpret_cast<unsigned*>(&hc);
        m.w = (unsigned)z[nn.x] | ((unsigned)z[nn.y] << 16);
    }
    meta[e] = m;
}

// ---------------------------------------------------------------------------
// Edge kernel, chunk-pipelined:
//  - meta double-buffered in LDS; next chunk loaded to regs BEFORE consume,
//    ds_written AFTER (global latency hidden under compute, no vmcnt drain)
//  - consume loop hand-rotated 2 deep with STATIC unroll (PC=16): iteration i
//    issues T-reads for i+1 and meta-read for i+2, computes/stores i.
// ---------------------------------------------------------------------------
__global__ __launch_bounds__(EBLOCK) void edge_kernel(
    const uint4* __restrict__ meta_g,  // [Epad]
    const float* __restrict__ tables,  // T1|T2|Wc in ws
    float* __restrict__ out,           // [E,128]
    int E, int BCH, int NCH)
{
    extern __shared__ float smem[];
    float* T1s = smem;                          // [100*128]
    float* T2s = smem + VOCAB * EMBED;          // [100*128]
    float* Wcs = smem + 2 * VOCAB * EMBED;      // [6*128]
    uint4* buf0 = (uint4*)(smem + TABLE_F);     // [CHUNK]
    uint4* buf1 = buf0 + CHUNK;                 // [CHUNK]

    const int tid  = threadIdx.x;
    const int base = blockIdx.x * BCH;
    const int lane = tid & 31;
    const int d    = lane * 4;
    const int g    = tid >> 5;
    const uint4* mg = meta_g + base;

    // ---- stage tables + chunk 0 ----
    {
        const float4* src = reinterpret_cast<const float4*>(tables);
        float4* dst = reinterpret_cast<float4*>(smem);
        #pragma unroll 2
        for (int i = tid; i < TABLE_F / 4; i += EBLOCK)
            dst[i] = src[i];
        if (tid < CHUNK)
            buf0[tid] = (tid < BCH) ? mg[tid] : make_uint4(0u, 0u, 0u, 0u);
    }
    __syncthreads();

    const float4 wc0 = *reinterpret_cast<const float4*>(Wcs + 0 * EMBED + d);
    const float4 wc1 = *reinterpret_cast<const float4*>(Wcs + 1 * EMBED + d);
    const float4 wc2 = *reinterpret_cast<const float4*>(Wcs + 2 * EMBED + d);
    const float4 wc3 = *reinterpret_cast<const float4*>(Wcs + 3 * EMBED + d);
    const float4 wc4 = *reinterpret_cast<const float4*>(Wcs + 4 * EMBED + d);
    const float4 wc5 = *reinterpret_cast<const float4*>(Wcs + 5 * EMBED + d);

    const int minE = min(BCH, E - base);            // valid edges this block
    const int lb = ((g >> 1) << 5) + (g & 1);       // pair-mapped group base

    int cur = 0;
    for (int c = 0; c < NCH; ++c) {
        // ---- issue next chunk's meta loads into registers (early) ----
        uint4 nx = make_uint4(0u, 0u, 0u, 0u);
        const bool have = (c + 1 < NCH) && (tid < CHUNK);
        if (have) {
            const int idx = (c + 1) * CHUNK + tid;
            if (idx < BCH) nx = mg[idx];
        }

        // ---- consume chunk c (2-deep rotated pipeline, static indices) ----
        const uint4* bufc = (cur == 0) ? buf0 : buf1;
        const int lim = minE - c * CHUNK;
        const int ebase = base + c * CHUNK;

        uint4 m0 = bufc[lb];
        uint4 m1 = bufc[lb + 2];
        float4 t1 = *reinterpret_cast<const float4*>(T1s + (((int)(m0.w & 0xffffu)) << 7) + d);
        float4 t2 = *reinterpret_cast<const float4*>(T2s + (((int)(m0.w >> 16)) << 7) + d);

        #pragma unroll
        for (int i = 0; i < PC; ++i) {
            float4 t1n = t1, t2n = t2;
            uint4 m2 = m1;
            if (i + 1 < PC) {
                t1n = *reinterpret_cast<const float4*>(T1s + (((int)(m1.w & 0xffffu)) << 7) + d);
                t2n = *reinterpret_cast<const float4*>(T2s + (((int)(m1.w >> 16)) << 7) + d);
            }
            if (i + 2 < PC) m2 = bufc[lb + 2 * (i + 2)];

            const float2 f01 = __half22float2(*reinterpret_cast<const __half2*>(&m0.x));
            const float2 f23 = __half22float2(*reinterpret_cast<const __half2*>(&m0.y));
            const float2 f45 = __half22float2(*reinterpret_cast<const __half2*>(&m0.z));

            float4 acc = t1;
            acc.x += t2.x; acc.y += t2.y; acc.z += t2.z; acc.w += t2.w;
            acc.x += f01.x * wc0.x; acc.y += f01.x * wc0.y; acc.z += f01.x * wc0.z; acc.w += f01.x * wc0.w;
            acc.x += f01.y * wc1.x; acc.y += f01.y * wc1.y; acc.z += f01.y * wc1.z; acc.w += f01.y * wc1.w;
            acc.x += f23.x * wc2.x; acc.y += f23.x * wc2.y; acc.z += f23.x * wc2.z; acc.w += f23.x * wc2.w;
            acc.x += f23.y * wc3.x; acc.y += f23.y * wc3.y; acc.z += f23.y * wc3.z; acc.w += f23.y * wc3.w;
            acc.x += f45.x * wc4.x; acc.y += f45.x * wc4.y; acc.z += f45.x * wc4.z; acc.w += f45.x * wc4.w;
            acc.x += f45.y * wc5.x; acc.y += f45.y * wc5.y; acc.z += f45.y * wc5.z; acc.w += f45.y * wc5.w;

            float4 rr;
            rr.x = acc.x * __builtin_amdgcn_rcpf(1.0f + __expf(-acc.x));
            rr.y = acc.y * __builtin_amdgcn_rcpf(1.0f + __expf(-acc.y));
            rr.z = acc.z * __builtin_amdgcn_rcpf(1.0f + __expf(-acc.z));
            rr.w = acc.w * __builtin_amdgcn_rcpf(1.0f + __expf(-acc.w));

            const int le = lb + 2 * i;
            if (le < lim)
                *reinterpret_cast<float4*>(out + (long)(ebase + le) * EMBED + d) = rr;

            m0 = m1; m1 = m2; t1 = t1n; t2 = t2n;
        }

        // ---- write next chunk's metas (late) + swap ----
        uint4* bufn = (cur == 0) ? buf1 : buf0;
        if (have) bufn[tid] = nx;
        __syncthreads();
        cur ^= 1;
    }
}

// ---------------------------------------------------------------------------
// Fallback (R8): used only if ws can't hold the meta array.
// ---------------------------------------------------------------------------
__global__ __launch_bounds__(EBLOCK) void edge_kernel_fb(
    const float* __restrict__ e_rbf,
    const int*   __restrict__ z,
    const int*   __restrict__ nbr,
    const float* __restrict__ tables,
    float* __restrict__ out, int E)
{
    extern __shared__ float smem[];
    float* T1s = smem;
    float* T2s = smem + VOCAB * EMBED;
    float* Wcs = smem + 2 * VOCAB * EMBED;
    uint4* meta = (uint4*)(smem + TABLE_F);

    const int tid  = threadIdx.x;
    const int base = blockIdx.x * BCHUNK;
    const int lane = tid & 31;
    const int d    = lane * 4;
    const int g    = tid >> 5;

    {
        const float4* src = reinterpret_cast<const float4*>(tables);
        float4* dst = reinterpret_cast<float4*>(smem);
        #pragma unroll 2
        for (int i = tid; i < TABLE_F / 4; i += EBLOCK)
            dst[i] = src[i];
    }
    for (int s = 0; s < 2; ++s) {
        const int idx = tid + s * EBLOCK;
        if (idx >= HALF_E) break;
        const int e = base + idx;
        uint4 m = make_uint4(0u, 0u, 0u, 0u);
        if (e < E) {
            const int2 nn = *reinterpret_cast<const int2*>(nbr + 2 * e);
            const float* rp = e_rbf + (long)e * NRBF;
            const float2 a = *reinterpret_cast<const float2*>(rp + 0);
            const float2 bb = *reinterpret_cast<const float2*>(rp + 2);
            const float2 c = *reinterpret_cast<const float2*>(rp + 4);
            __half2 ha = __float22half2_rn(a);
            __half2 hb = __float22half2_rn(bb);
            __half2 hc = __float22half2_rn(c);
            m.x = *reinterpret_cast<unsigned*>(&ha);
            m.y = *reinterpret_cast<unsigned*>(&hb);
            m.z = *reinterpret_cast<unsigned*>(&hc);
            m.w = (unsigned)z[nn.x] | ((unsigned)z[nn.y] << 16);
        }
        meta[idx] = m;
    }

    int2 nnA = make_int2(0, 0);
    float2 rA0 = make_float2(0.f, 0.f), rA1 = rA0, rA2 = rA0;
    int2 nnB = make_int2(0, 0);
    float2 rB0 = make_float2(0.f, 0.f), rB1 = rB0, rB2 = rB0;
    const int eA = base + HALF_E + tid;
    const bool vA = (eA < E);
    const int eB = base + HALF_E + EBLOCK + tid;
    const bool vB = (tid < HALF_E - EBLOCK) && (eB < E);
    if (vA) {
        nnA = *reinterpret_cast<const int2*>(nbr + 2 * eA);
        const float* rp = e_rbf + (long)eA * NRBF;
        rA0 = *reinterpret_cast<const float2*>(rp + 0);
        rA1 = *reinterpret_cast<const float2*>(rp + 2);
        rA2 = *reinterpret_cast<const float2*>(rp + 4);
    }
    if (vB) {
        nnB = *reinterpret_cast<const int2*>(nbr + 2 * eB);
        const float* rp = e_rbf + (long)eB * NRBF;
        rB0 = *reinterpret_cast<const float2*>(rp + 0);
        rB1 = *reinterpret_cast<const float2*>(rp + 2);
        rB2 = *reinterpret_cast<const float2*>(rp + 4);
    }
    __syncthreads();

    const float4 wc0 = *reinterpret_cast<const float4*>(Wcs + 0 * EMBED + d);
    const float4 wc1 = *reinterpret_cast<const float4*>(Wcs + 1 * EMBED + d);
    const float4 wc2 = *reinterpret_cast<const float4*>(Wcs + 2 * EMBED + d);
    const float4 wc3 = *reinterpret_cast<const float4*>(Wcs + 3 * EMBED + d);
    const float4 wc4 = *reinterpret_cast<const float4*>(Wcs + 4 * EMBED + d);
    const float4 wc5 = *reinterpret_cast<const float4*>(Wcs + 5 * EMBED + d);

    auto consume_half = [&](int ebase) {
        const int lb = (g >> 1) * (2 * CPG) + (g & 1);
        #pragma unroll 4
        for (int i = 0; i < CPG; ++i) {
            const int le = lb + 2 * i;
            const int e = ebase + le;
            if (e >= E) break;
            const uint4 m = meta[le];
            const float2 f01 = __half22float2(*reinterpret_cast<const __half2*>(&m.x));
            const float2 f23 = __half22float2(*reinterpret_cast<const __half2*>(&m.y));
            const float2 f45 = __half22float2(*reinterpret_cast<const __half2*>(&m.z));
            const int za = (int)(m.w & 0xffffu) << 7;
            const int zb = (int)(m.w >> 16) << 7;

            float4 acc = *reinterpret_cast<const float4*>(T1s + za + d);
            const float4 t2 = *reinterpret_cast<const float4*>(T2s + zb + d);
            acc.x += t2.x; acc.y += t2.y; acc.z += t2.z; acc.w += t2.w;
            acc.x += f01.x * wc0.x; acc.y += f01.x * wc0.y; acc.z += f01.x * wc0.z; acc.w += f01.x * wc0.w;
            acc.x += f01.y * wc1.x; acc.y += f01.y * wc1.y; acc.z += f01.y * wc1.z; acc.w += f01.y * wc1.w;
            acc.x += f23.x * wc2.x; acc.y += f23.x * wc2.y; acc.z += f23.x * wc2.z; acc.w += f23.x * wc2.w;
            acc.x += f23.y * wc3.x; acc.y += f23.y * wc3.y; acc.z += f23.y * wc3.z; acc.w += f23.y * wc3.w;
            acc.x += f45.x * wc4.x; acc.y += f45.x * wc4.y; acc.z += f45.x * wc4.z; acc.w += f45.x * wc4.w;
            acc.x += f45.y * wc5.x; acc.y += f45.y * wc5.y; acc.z += f45.y * wc5.z; acc.w += f45.y * wc5.w;

            float4 rr;
            rr.x = acc.x * __builtin_amdgcn_rcpf(1.0f + __expf(-acc.x));
            rr.y = acc.y * __builtin_amdgcn_rcpf(1.0f + __expf(-acc.y));
            rr.z = acc.z * __builtin_amdgcn_rcpf(1.0f + __expf(-acc.z));
            rr.w = acc.w * __builtin_amdgcn_rcpf(1.0f + __expf(-acc.w));
            *reinterpret_cast<float4*>(out + (long)e * EMBED + d) = rr;
        }
    };

    consume_half(base);
    __syncthreads();
    if (tid < HALF_E) {
        uint4 m = make_uint4(0u, 0u, 0u, 0u);
        if (vA) {
            __half2 ha = __float22half2_rn(rA0);
            __half2 hb = __float22half2_rn(rA1);
            __half2 hc = __float22half2_rn(rA2);
            m.x = *reinterpret_cast<unsigned*>(&ha);
            m.y = *reinterpret_cast<unsigned*>(&hb);
            m.z = *reinterpret_cast<unsigned*>(&hc);
            m.w = (unsigned)z[nnA.x] | ((unsigned)z[nnA.y] << 16);
        }
        meta[tid] = m;
    }
    if (tid < HALF_E - EBLOCK) {
        uint4 m = make_uint4(0u, 0u, 0u, 0u);
        if (vB) {
            __half2 ha = __float22half2_rn(rB0);
            __half2 hb = __float22half2_rn(rB1);
            __half2 hc = __float22half2_rn(rB2);
            m.x = *reinterpret_cast<unsigned*>(&ha);
            m.y = *reinterpret_cast<unsigned*>(&hb);
            m.z = *reinterpret_cast<unsigned*>(&hc);
            m.w = (unsigned)z[nnB.x] | ((unsigned)z[nnB.y] << 16);
        }
        meta[EBLOCK + tid] = m;
    }
    __syncthreads();
    consume_half(base + HALF_E);
}

extern "C" void kernel_launch(void* const* d_in, const int* in_sizes, int n_in,
                              void* d_out, int out_size, void* d_ws, size_t ws_size,
                              hipStream_t stream)
{
    // Input order: e_rbf, z, nbr_list, W_edge, emb_table, W_dense, b_dense
    const float* e_rbf  = (const float*)d_in[0];
    const int*   z      = (const int*)  d_in[1];
    const int*   nbr    = (const int*)  d_in[2];
    const float* W_edge = (const float*)d_in[3];
    const float* emb    = (const float*)d_in[4];
    const float* Wd     = (const float*)d_in[5];
    const float* b      = (const float*)d_in[6];
    float* out = (float*)d_out;

    const int E = in_sizes[2] / 2;

    float* T1 = (float*)d_ws;
    float* T2 = T1 + VOCAB * EMBED;
    float* Wc = T2 + VOCAB * EMBED;
    uint4* meta = (uint4*)((char*)d_ws + TABLE_F * 4);

    precompute_kernel<<<2 * VOCAB + NRBF, EMBED, 0, stream>>>(W_edge, emb, Wd, b, T1, T2, Wc);

    const int BCH  = (E + EGRID - 1) / EGRID;        // 2344
    const int NCH  = (BCH + CHUNK - 1) / CHUNK;      // 5
    const int Epad = EGRID * BCH;                    // 600064
    const size_t need = (size_t)TABLE_F * 4 + (size_t)Epad * 16;

    if (ws_size >= need) {
        pack_kernel<<<(Epad + 255) / 256, 256, 0, stream>>>(e_rbf, z, nbr, meta, E, Epad);
        edge_kernel<<<EGRID, EBLOCK, SMEM_MAIN, stream>>>(meta, T1, out, E, BCH, NCH);
    } else {
        const int grid = (E + BCHUNK - 1) / BCHUNK;
        edge_kernel_fb<<<grid, EBLOCK, SMEM_FB, stream>>>(e_rbf, z, nbr, T1, out, E);
    }
}

// Round 10
// 75.657 us; speedup vs baseline: 1.1192x; 1.1192x over previous
//
#include <hip/hip_runtime.h>
#include <hip/hip_fp16.h>

#define EMBED 128
#define NRBF 6
#define VOCAB 100
#define EBLOCK 1024
#define GROUPS 32                   // 32-lane groups per block
#define CPG 19                      // edges per group per half
#define HALF_E (GROUPS * CPG / 2 * 2)          // 608 (16 pairs * 38)
#define BCHUNK (2 * HALF_E)                    // 1216
// tables: T1h,T2h fp16 [100][128] + Wc fp32 [6][128]
#define T_HALFS (VOCAB * EMBED)                // 12800 halfs per table
#define TABLE_BYTES (2 * T_HALFS * 2 + NRBF * EMBED * 4)   // 51200 + 3072 = 54,272
#define SMEM_BYTES (TABLE_BYTES + HALF_E * 16)             // 63,  54,272+9,728 = 64,000

// ---------------------------------------------------------------------------
// Precompute (206 blocks):
//   T1h[v][d] = fp16( sum_j emb[v][j]*Wd[j][d] + b[d] )
//   T2h[v][d] = fp16( sum_j emb[v][j]*Wd[128+j][d] )
//   Wc[k][d]  = fp32( sum_j W_edge[k][j]*Wd[256+j][d] )
// ---------------------------------------------------------------------------
__global__ __launch_bounds__(EMBED) void precompute_kernel(
    const float* __restrict__ W_edge,
    const float* __restrict__ emb,
    const float* __restrict__ Wd,
    const float* __restrict__ b,
    __half* __restrict__ T1h,
    __half* __restrict__ T2h,
    float* __restrict__ Wc)
{
    const int d = threadIdx.x;
    const int v = blockIdx.x;
    if (v < 2 * VOCAB) {
        const int row = (v < VOCAB) ? v : v - VOCAB;
        const int woff = (v < VOCAB) ? 0 : EMBED;
        __shared__ float hrow[EMBED];
        hrow[d] = emb[row * EMBED + d];
        __syncthreads();
        float acc = (v < VOCAB) ? b[d] : 0.0f;
        #pragma unroll 8
        for (int j = 0; j < EMBED; ++j)
            acc += hrow[j] * Wd[(woff + j) * EMBED + d];
        if (v < VOCAB) T1h[row * EMBED + d] = __float2half_rn(acc);
        else           T2h[row * EMBED + d] = __float2half_rn(acc);
    } else {
        const int k = v - 2 * VOCAB;
        float acc = 0.0f;
        #pragma unroll 8
        for (int j = 0; j < EMBED; ++j)
            acc += W_edge[k * EMBED + j] * Wd[(2 * EMBED + j) * EMBED + d];
        Wc[k * EMBED + d] = acc;
    }
}

// ---------------------------------------------------------------------------
// Edge kernel. fp16 tables (53 KB LDS) -> ds_read_b64 table reads, 64 KB LDS
// total -> TWO blocks per CU (32 waves) so stage/barrier phases of one block
// overlap the store stream of the other.
// Per half: threads 0..607 stage meta {6x fp16 rbf, z[a]|z[b]<<16}; consume
// loop reads meta (b128 bcast) + T1h/T2h (b64), fp16 add, fp32 FMA + silu,
// one contiguous 1 KB store per wave (pair-mapped groups).
// ---------------------------------------------------------------------------
__global__ __launch_bounds__(EBLOCK, 8) void edge_kernel(
    const float* __restrict__ e_rbf,   // [E,6]
    const int*   __restrict__ z,       // [N]
    const int*   __restrict__ nbr,     // [E,2]
    const float* __restrict__ tables,  // T1h|T2h|Wc in ws (54,272 B)
    float* __restrict__ out,           // [E,128]
    int E)
{
    extern __shared__ char smemraw[];
    __half* T1s = (__half*)smemraw;                        // [12800]
    __half* T2s = T1s + T_HALFS;                           // [12800]
    float*  Wcs = (float*)(smemraw + 2 * T_HALFS * 2);     // [768]
    uint4*  meta = (uint4*)(smemraw + TABLE_BYTES);        // [608]

    const int tid  = threadIdx.x;
    const int base = blockIdx.x * BCHUNK;
    const int lane = tid & 31;
    const int d    = lane * 4;
    const int g    = tid >> 5;

    // ---- stage tables (54,272 B as float4s) ----
    {
        const float4* src = reinterpret_cast<const float4*>(tables);
        float4* dst = reinterpret_cast<float4*>(smemraw);
        #pragma unroll 2
        for (int i = tid; i < TABLE_BYTES / 16; i += EBLOCK)
            dst[i] = src[i];
    }

    auto stage_half = [&](int ebase) {
        if (tid < HALF_E) {
            const int e = ebase + tid;
            uint4 m = make_uint4(0u, 0u, 0u, 0u);
            if (e < E) {
                const int2 nn = *reinterpret_cast<const int2*>(nbr + 2 * e);
                const float* rp = e_rbf + (long)e * NRBF;
                const float2 a  = *reinterpret_cast<const float2*>(rp + 0);
                const float2 bb = *reinterpret_cast<const float2*>(rp + 2);
                const float2 c  = *reinterpret_cast<const float2*>(rp + 4);
                __half2 ha = __float22half2_rn(a);
                __half2 hb = __float22half2_rn(bb);
                __half2 hc = __float22half2_rn(c);
                m.x = *reinterpret_cast<unsigned*>(&ha);
                m.y = *reinterpret_cast<unsigned*>(&hb);
                m.z = *reinterpret_cast<unsigned*>(&hc);
                m.w = (unsigned)z[nn.x] | ((unsigned)z[nn.y] << 16);
            }
            meta[tid] = m;
        }
    };

    // ---- stage half 0 ----
    stage_half(base);
    __syncthreads();

    // Wc into registers (24 VGPR, invariant)
    const float4 wc0 = *reinterpret_cast<const float4*>(Wcs + 0 * EMBED + d);
    const float4 wc1 = *reinterpret_cast<const float4*>(Wcs + 1 * EMBED + d);
    const float4 wc2 = *reinterpret_cast<const float4*>(Wcs + 2 * EMBED + d);
    const float4 wc3 = *reinterpret_cast<const float4*>(Wcs + 3 * EMBED + d);
    const float4 wc4 = *reinterpret_cast<const float4*>(Wcs + 4 * EMBED + d);
    const float4 wc5 = *reinterpret_cast<const float4*>(Wcs + 5 * EMBED + d);

    auto consume_half = [&](int ebase) {
        const int lb = (g >> 1) * (2 * CPG) + (g & 1);   // pair-mapped
        #pragma unroll
        for (int i = 0; i < CPG; ++i) {
            const int le = lb + 2 * i;
            const int e = ebase + le;

            const uint4 m = meta[le];                    // ds_read_b128 bcast
            const int za = (int)(m.w & 0xffffu) << 7;
            const int zb = (int)(m.w >> 16) << 7;

            // fp16 table reads (ds_read_b64) + packed fp16 add
            const uint2 t1p = *reinterpret_cast<const uint2*>(T1s + za + d);
            const uint2 t2p = *reinterpret_cast<const uint2*>(T2s + zb + d);
            const __half2 s0 = __hadd2(*reinterpret_cast<const __half2*>(&t1p.x),
                                       *reinterpret_cast<const __half2*>(&t2p.x));
            const __half2 s1 = __hadd2(*reinterpret_cast<const __half2*>(&t1p.y),
                                       *reinterpret_cast<const __half2*>(&t2p.y));
            const float2 a01 = __half22float2(s0);
            const float2 a23 = __half22float2(s1);
            float4 acc = make_float4(a01.x, a01.y, a23.x, a23.y);

            const float2 f01 = __half22float2(*reinterpret_cast<const __half2*>(&m.x));
            const float2 f23 = __half22float2(*reinterpret_cast<const __half2*>(&m.y));
            const float2 f45 = __half22float2(*reinterpret_cast<const __half2*>(&m.z));

            acc.x += f01.x * wc0.x; acc.y += f01.x * wc0.y; acc.z += f01.x * wc0.z; acc.w += f01.x * wc0.w;
            acc.x += f01.y * wc1.x; acc.y += f01.y * wc1.y; acc.z += f01.y * wc1.z; acc.w += f01.y * wc1.w;
            acc.x += f23.x * wc2.x; acc.y += f23.x * wc2.y; acc.z += f23.x * wc2.z; acc.w += f23.x * wc2.w;
            acc.x += f23.y * wc3.x; acc.y += f23.y * wc3.y; acc.z += f23.y * wc3.z; acc.w += f23.y * wc3.w;
            acc.x += f45.x * wc4.x; acc.y += f45.x * wc4.y; acc.z += f45.x * wc4.z; acc.w += f45.x * wc4.w;
            acc.x += f45.y * wc5.x; acc.y += f45.y * wc5.y; acc.z += f45.y * wc5.z; acc.w += f45.y * wc5.w;

            float4 rr;
            rr.x = acc.x * __builtin_amdgcn_rcpf(1.0f + __expf(-acc.x));
            rr.y = acc.y * __builtin_amdgcn_rcpf(1.0f + __expf(-acc.y));
            rr.z = acc.z * __builtin_amdgcn_rcpf(1.0f + __expf(-acc.z));
            rr.w = acc.w * __builtin_amdgcn_rcpf(1.0f + __expf(-acc.w));

            if (e < E)
                *reinterpret_cast<float4*>(out + (long)e * EMBED + d) = rr;
        }
    };

    // ---- consume half 0 ----
    consume_half(base);
    __syncthreads();

    // ---- stage + consume half 1 ----
    stage_half(base + HALF_E);
    __syncthreads();
    consume_half(base + HALF_E);
}

extern "C" void kernel_launch(void* const* d_in, const int* in_sizes, int n_in,
                              void* d_out, int out_size, void* d_ws, size_t ws_size,
                              hipStream_t stream)
{
    // Input order: e_rbf, z, nbr_list, W_edge, emb_table, W_dense, b_dense
    const float* e_rbf  = (const float*)d_in[0];
    const int*   z      = (const int*)  d_in[1];
    const int*   nbr    = (const int*)  d_in[2];
    const float* W_edge = (const float*)d_in[3];
    const float* emb    = (const float*)d_in[4];
    const float* Wd     = (const float*)d_in[5];
    const float* b      = (const float*)d_in[6];
    float* out = (float*)d_out;

    const int E = in_sizes[2] / 2;

    // ws layout: T1h (12800 half) | T2h (12800 half) | Wc (768 float)
    __half* T1h = (__half*)d_ws;
    __half* T2h = T1h + T_HALFS;
    float*  Wc  = (float*)((char*)d_ws + 2 * T_HALFS * 2);

    precompute_kernel<<<2 * VOCAB + NRBF, EMBED, 0, stream>>>(W_edge, emb, Wd, b, T1h, T2h, Wc);

    const int grid = (E + BCHUNK - 1) / BCHUNK;   // 494 for E=600000
    edge_kernel<<<grid, EBLOCK, SMEM_BYTES, stream>>>(e_rbf, z, nbr, (const float*)d_ws, out, E);
}